// Round 13
// baseline (38.634 us; speedup 1.0000x reference)
//
#include <hip/hip_runtime.h>

#define NPTS   16384
#define RPB    256      // rows per block (4 waves x 64)
#define CPB    512      // cols per block
#define NRB    (NPTS / RPB)   // 64
#define NCB    (NPTS / CPB)   // 32

typedef short  bf16x8 __attribute__((ext_vector_type(8)));
typedef float  f32x16 __attribute__((ext_vector_type(16)));

// ---- bf16 split helpers (RNE) ----
__device__ __forceinline__ unsigned rne_bf16(float f) {
    unsigned u = __float_as_uint(f);
    return (u + 0x7fffu + ((u >> 16) & 1u)) >> 16;
}
__device__ __forceinline__ float bf16_dec(unsigned h) {
    return __uint_as_float(h << 16);
}
#define ONE_BF 0x3f80u

// min3-tree over one acc's 16 elements (all literal indices -> pure registers)
__device__ __forceinline__ float tree16_min(f32x16 a) {
    float x0 = fminf(fminf(a[0],  a[1]),  a[2]);    // v_min3 x5
    float x1 = fminf(fminf(a[3],  a[4]),  a[5]);
    float x2 = fminf(fminf(a[6],  a[7]),  a[8]);
    float x3 = fminf(fminf(a[9],  a[10]), a[11]);
    float x4 = fminf(fminf(a[12], a[13]), a[14]);
    float y0 = fminf(fminf(x0, x1), x2);            // v_min3 x2
    float y1 = fminf(fminf(x3, x4), a[15]);
    return fminf(y0, y1);
}

// K=16 slot map (A = weighted pred, B = plain tgt):
//  k0-3: ah*bh  k4-7: al*bh  k8-11: ah*bl  k12-13: 1*Tnh,1*Tnl  k14-15: Pnh*1,Pnl*1
// => acc = hi-precision dot + Tn_j + Pn_i = combined(i,j) directly.
// combined() is symmetric in (pred,tgt): row-mins of M = min_p2g,
// col-mins of M = min_g2p. ONE pass serves both directions.

__global__ __launch_bounds__(256) void prep_kernel(
    const float4* __restrict__ pred, const float4* __restrict__ tgt,
    uint4* __restrict__ wpred, uint4* __restrict__ ptgt)
{
    int i = blockIdx.x * 256 + threadIdx.x;
    if (i >= NPTS) return;

    unsigned onepk = ONE_BF | (ONE_BF << 16);

    {   // weighted pred record (row side)
        float4 v = pred[i];
        float n = fmaf(v.x, v.x, fmaf(v.y, v.y, fmaf(v.z, v.z, 0.5f * v.w * v.w)));
        unsigned nh = rne_bf16(n);
        unsigned nl = rne_bf16(n - bf16_dec(nh));
        unsigned npk = nh | (nl << 16);
        float w0 = -2.0f * v.x, w1 = -2.0f * v.y, w2 = -2.0f * v.z, w3 = -v.w;
        unsigned h0 = rne_bf16(w0), h1 = rne_bf16(w1), h2 = rne_bf16(w2), h3 = rne_bf16(w3);
        unsigned l0 = rne_bf16(w0 - bf16_dec(h0)), l1 = rne_bf16(w1 - bf16_dec(h1));
        unsigned l2 = rne_bf16(w2 - bf16_dec(h2)), l3 = rne_bf16(w3 - bf16_dec(h3));
        wpred[i * 2 + 0] = make_uint4(h0 | (h1 << 16), h2 | (h3 << 16),
                                      l0 | (l1 << 16), l2 | (l3 << 16));   // [ah, al]
        wpred[i * 2 + 1] = make_uint4(h0 | (h1 << 16), h2 | (h3 << 16),
                                      onepk, npk);                          // [ah, 1,1, Pnh,Pnl]
    }
    {   // plain tgt record (col side)
        float4 v = tgt[i];
        float n = fmaf(v.x, v.x, fmaf(v.y, v.y, fmaf(v.z, v.z, 0.5f * v.w * v.w)));
        unsigned nh = rne_bf16(n);
        unsigned nl = rne_bf16(n - bf16_dec(nh));
        unsigned npk = nh | (nl << 16);
        unsigned g0 = rne_bf16(v.x), g1 = rne_bf16(v.y), g2 = rne_bf16(v.z), g3 = rne_bf16(v.w);
        unsigned m0 = rne_bf16(v.x - bf16_dec(g0)), m1 = rne_bf16(v.y - bf16_dec(g1));
        unsigned m2 = rne_bf16(v.z - bf16_dec(g2)), m3 = rne_bf16(v.w - bf16_dec(g3));
        ptgt[i * 2 + 0] = make_uint4(g0 | (g1 << 16), g2 | (g3 << 16),
                                     g0 | (g1 << 16), g2 | (g3 << 16));     // [bh, bh]
        ptgt[i * 2 + 1] = make_uint4(m0 | (m1 << 16), m2 | (m3 << 16),
                                     npk, onepk);                           // [bl, Tnh,Tnl, 1,1]
    }
}

// R12 post-mortem: 1.57M global atomicMin (768/block x 2048 blocks, 32-64-way
// same-address contention) dominated (~10-15us of L2 serialization). R13:
// per-block partials -> DISTINCT slots via plain coalesced stores (3KB/block);
// cross-block min moves to reduce1. No atomics, no sentinel init, fully
// deterministic. Main loop identical to the no-spill R12.
__global__ __launch_bounds__(256, 4) void chamfer_mfma_kernel(
    const bf16x8* __restrict__ wpred, const bf16x8* __restrict__ ptgt,
    float* __restrict__ rowpart,    // [NCB][NPTS]
    float* __restrict__ colpart)    // [NRB][NPTS]
{
    __shared__ unsigned colLds[CPB];   // block-wide col mins (clamped bits)
    __shared__ float red[RPB];         // block-wide row mins

    for (int c = threadIdx.x; c < CPB; c += 256) colLds[c] = 0x7f7f7f7fu;
    __syncthreads();

    const int lane = threadIdx.x & 63;
    const int wave = threadIdx.x >> 6;
    const int half = lane >> 5;     // selects k0-7 vs k8-15 record
    const int lid  = lane & 31;

    const int rowBase = blockIdx.x * RPB + wave * 64;
    const int colBase = blockIdx.y * CPB;

    bf16x8 a0 = wpred[(rowBase +      lid) * 2 + half];
    bf16x8 a1 = wpred[(rowBase + 32 + lid) * 2 + half];

    float mr0[16], mr1[16];
#pragma unroll
    for (int r = 0; r < 16; ++r) { mr0[r] = 3.0e38f; mr1[r] = 3.0e38f; }

    const bf16x8* bp = ptgt + (colBase + lid) * 2 + half;
    const f32x16 kZero = (f32x16)(0.0f);

#pragma unroll 2
    for (int t = 0; t < CPB / 64; ++t) {
        bf16x8 b0 = bp[t * 128];
        bf16x8 b1 = bp[t * 128 + 64];

        // row-tile 0 (rows 0-31)
        f32x16 A0 = __builtin_amdgcn_mfma_f32_32x32x16_bf16(a0, b0, kZero, 0, 0, 0);
        f32x16 A1 = __builtin_amdgcn_mfma_f32_32x32x16_bf16(a0, b1, kZero, 0, 0, 0);
#pragma unroll
        for (int r = 0; r < 16; ++r)
            mr0[r] = fminf(fminf(A0[r], A1[r]), mr0[r]);   // v_min3
        float ta = tree16_min(A0);
        float tb = tree16_min(A1);
        __builtin_amdgcn_sched_barrier(0x20);   // retire A0/A1; loads may cross

        // row-tile 1 (rows 32-63)
        f32x16 B0 = __builtin_amdgcn_mfma_f32_32x32x16_bf16(a1, b0, kZero, 0, 0, 0);
        f32x16 B1 = __builtin_amdgcn_mfma_f32_32x32x16_bf16(a1, b1, kZero, 0, 0, 0);
#pragma unroll
        for (int r = 0; r < 16; ++r)
            mr1[r] = fminf(fminf(B0[r], B1[r]), mr1[r]);
        ta = fminf(ta, tree16_min(B0));
        tb = fminf(tb, tree16_min(B1));
        __builtin_amdgcn_sched_barrier(0x20);   // retire B0/B1

        // col flush (in-block only): col = t*64 + (0|32) + lid
        atomicMin(&colLds[t * 64 +      lid], __float_as_uint(fmaxf(ta, 0.0f)));
        atomicMin(&colLds[t * 64 + 32 + lid], __float_as_uint(fmaxf(tb, 0.0f)));
    }

    // row mins: cross-lane min over the 32 col-lanes
    // C/D layout: col=lane&31, row=(reg&3)+8*(reg>>2)+4*(lane>>5)
#pragma unroll
    for (int r = 0; r < 16; ++r) {
        float v0 = mr0[r], v1 = mr1[r];
        v0 = fminf(v0, __shfl_xor(v0, 16)); v1 = fminf(v1, __shfl_xor(v1, 16));
        v0 = fminf(v0, __shfl_xor(v0, 8));  v1 = fminf(v1, __shfl_xor(v1, 8));
        v0 = fminf(v0, __shfl_xor(v0, 4));  v1 = fminf(v1, __shfl_xor(v1, 4));
        v0 = fminf(v0, __shfl_xor(v0, 2));  v1 = fminf(v1, __shfl_xor(v1, 2));
        v0 = fminf(v0, __shfl_xor(v0, 1));  v1 = fminf(v1, __shfl_xor(v1, 1));
        if (lid == 0) {
            int row = (r & 3) + 8 * (r >> 2) + 4 * half;
            red[wave * 64 + row]      = v0;
            red[wave * 64 + 32 + row] = v1;
        }
    }
    __syncthreads();

    // per-block partials -> distinct slots, plain coalesced stores
    rowpart[blockIdx.y * NPTS + blockIdx.x * RPB + threadIdx.x] =
        fmaxf(red[threadIdx.x], 0.0f);
#pragma unroll
    for (int s = 0; s < 2; ++s) {
        int c = threadIdx.x + s * 256;
        colpart[blockIdx.x * NPTS + colBase + c] = __uint_as_float(colLds[c]);
    }
}

// blocks 0-63: rows (min over NCB=32 partials); blocks 64-127: cols (NRB=64).
__global__ __launch_bounds__(256) void reduce1_kernel(
    const float* __restrict__ rowpart, const float* __restrict__ colpart,
    float* __restrict__ partsum)
{
    const int b = blockIdx.x, t = threadIdx.x;
    float m;
    if (b < 64) {
        int r = b * 256 + t;
        m = rowpart[r];
#pragma unroll
        for (int k = 1; k < NCB; ++k) m = fminf(m, rowpart[k * NPTS + r]);
    } else {
        int c = (b - 64) * 256 + t;
        m = colpart[c];
#pragma unroll
        for (int k = 1; k < NRB; ++k) m = fminf(m, colpart[k * NPTS + c]);
    }
    float s = m;
#pragma unroll
    for (int off = 32; off > 0; off >>= 1) s += __shfl_down(s, off);
    __shared__ float red[4];
    if ((t & 63) == 0) red[t >> 6] = s;
    __syncthreads();
    if (t == 0) partsum[b] = red[0] + red[1] + red[2] + red[3];
}

__global__ __launch_bounds__(64) void finalize_kernel(
    const float* __restrict__ partsum, float* __restrict__ out)
{
    const int t = threadIdx.x;
    float s = partsum[t] + partsum[t + 64];
#pragma unroll
    for (int off = 32; off > 0; off >>= 1) s += __shfl_down(s, off);
    if (t == 0) out[0] = s * (1.0f / (float)NPTS);
}

extern "C" void kernel_launch(void* const* d_in, const int* in_sizes, int n_in,
                              void* d_out, int out_size, void* d_ws, size_t ws_size,
                              hipStream_t stream) {
    const float4* pred = (const float4*)d_in[0];
    const float4* tgt  = (const float4*)d_in[1];

    char* ws = (char*)d_ws;
    float* rowpart = (float*)ws;                          // 32*16384*4 = 2 MB
    float* colpart = (float*)(ws + (2u << 20));           // 64*16384*4 = 4 MB
    float* partsum = (float*)(ws + (6u << 20));           // 128 floats
    uint4* wpred   = (uint4*)(ws + (6u << 20) + 4096);    // 512 KB
    uint4* ptgt    = wpred + 2 * NPTS;                    // 512 KB

    prep_kernel<<<NPTS / 256, 256, 0, stream>>>(pred, tgt, wpred, ptgt);

    dim3 grid(NRB, NCB);   // (64, 32) = 2048 blocks, single pass over M
    chamfer_mfma_kernel<<<grid, 256, 0, stream>>>(
        (const bf16x8*)wpred, (const bf16x8*)ptgt, rowpart, colpart);

    reduce1_kernel<<<128, 256, 0, stream>>>(rowpart, colpart, partsum);
    finalize_kernel<<<1, 64, 0, stream>>>(partsum, (float*)d_out);
}